// Round 15
// baseline (184.033 us; speedup 1.0000x reference)
//
#include <hip/hip_runtime.h>

#define NB 4
#define NC 64
#define NV (48*48*48)
#define NA 64
#define NE 128

typedef __attribute__((ext_vector_type(8))) short short8;
typedef __attribute__((ext_vector_type(4))) float f32x4;
typedef __attribute__((ext_vector_type(16))) float f32x16;

static __device__ __forceinline__ ushort f2bf(float f) {
  unsigned u = __float_as_uint(f);
  unsigned r = (u + 0x7FFF + ((u >> 16) & 1)) >> 16;
  return (ushort)r;
}
static __device__ __forceinline__ unsigned pk2bf(float lo, float hi) {
  return (unsigned)f2bf(lo) | ((unsigned)f2bf(hi) << 16);
}

// ---- kernel 1a: vmat[b][a][c] = me @ v_w^T + v_b  (64 blocks, parallel) ----
__global__ __launch_bounds__(256) void k_vm(
    const float* __restrict__ me, const float* __restrict__ vw,
    const float* __restrict__ vb, float* __restrict__ vmat) {
  int blk = blockIdx.x;
  int b = blk >> 4, aq = blk & 15;
  int t = threadIdx.x;
  int a = aq * 4 + (t >> 6);
  int c = t & 63;
  const float* mp = me + (size_t)(b * 64 + a) * 128;
  const float* wp = vw + (size_t)c * 128;
  float acc = vb[c];
#pragma unroll 8
  for (int e = 0; e < 128; e += 4) {
    float4 m4 = *(const float4*)(mp + e);
    float4 w4 = *(const float4*)(wp + e);
    acc += m4.x * w4.x + m4.y * w4.y + m4.z * w4.z + m4.w * w4.w;
  }
  vmat[b * 4096 + a * 64 + c] = acc;
}

// ---- kernel 1c: BcT[b][o][128]: k<64 -> u[k][o]=VM@W_v^T, k>=64 -> W_x -----
__global__ __launch_bounds__(256) void k_bct(
    const float* __restrict__ ow, const float* __restrict__ vmat,
    ushort* __restrict__ BcT) {
  __shared__ float VM[64 * 68];
  __shared__ float WV[8 * 68];
  int blk = blockIdx.x;
  int b = blk >> 3, og = blk & 7;
  int t = threadIdx.x;
  for (int i = t; i < 4096; i += 256)
    VM[(i >> 6) * 68 + (i & 63)] = vmat[b * 4096 + i];
  for (int i = t; i < 512; i += 256)
    WV[(i >> 6) * 68 + (i & 63)] = ow[(og * 8 + (i >> 6)) * 128 + 64 + (i & 63)];
  __syncthreads();
  int ol = t >> 5;
  int a0 = (t & 31) * 2;
  int o = og * 8 + ol;
#pragma unroll
  for (int p = 0; p < 2; ++p) {
    int a = a0 + p;
    float acc = 0.f;
#pragma unroll 8
    for (int c = 0; c < 64; c += 4) {
      float4 v4 = *(const float4*)&VM[a * 68 + c];
      float4 w4 = *(const float4*)&WV[ol * 68 + c];
      acc += v4.x * w4.x + v4.y * w4.y + v4.z * w4.z + v4.w * w4.w;
    }
    BcT[b * 8192 + o * 128 + a] = f2bf(acc);
  }
#pragma unroll
  for (int p = 0; p < 2; ++p) {
    int i = t * 2 + p;
    int ol2 = i >> 6, ci = i & 63;
    int o2 = og * 8 + ol2;
    BcT[b * 8192 + o2 * 128 + 64 + ci] = f2bf(ow[o2 * 128 + ci]);
  }
}

// --- kernel 1b: conv weights -> bf16 frag-major for 32x32x16 MFMA ------------
__global__ void k_wt(const float* __restrict__ cw, ushort* __restrict__ wbf) {
  int idx = blockIdx.x * 256 + threadIdx.x;
  if (idx >= 27 * 64 * 64) return;
  int off = idx >> 12, r = idx & 4095;
  int kcw = r >> 11, r2 = r & 2047;
  int nt = r2 >> 10, r3 = r2 & 1023;
  int kk = r3 >> 9, r4 = r3 & 511;
  int ln = r4 >> 3, e = r4 & 7;
  int co = nt * 32 + (ln & 31);
  int ci = kcw * 32 + kk * 16 + (ln >> 5) * 8 + e;
  wbf[idx] = f2bf(cw[(co * 64 + ci) * 27 + off]);
}

// -------- kernel 2: 1-WAVE blocks (32 vox), barrier-cheap, on-demand Bf ------
__global__ __launch_bounds__(64) void k_att2(
    const float* __restrict__ x, const float* __restrict__ pos,
    const float* __restrict__ origin, const float* __restrict__ lattice,
    const int* __restrict__ bnodes, const float* __restrict__ ob,
    const ushort* __restrict__ BcT, ushort* __restrict__ hbf) {
  __shared__ __align__(16) char Ac[8192];    // [32 rows][256 B], slot^(row&7)
  __shared__ float ps[192];
  __shared__ float sinv[32];
  int t = threadIdx.x;                       // 0..63 (one wave)
  int b = blockIdx.y;
  int v0 = blockIdx.x * 32;
  int lm = t & 15, lg = t >> 4;              // lg 0..3

  for (int i = t; i < 192; i += 64) ps[i] = pos[b * 192 + i];
  __syncthreads();                           // 1-wave: just a drain, cheap

  // dist + exp -> Ac slots 0..7 (unnormalized), sinv
  {
    int v_loc = t & 31;
    int half = t >> 5;
    int v = v0 + v_loc;
    int ix = v / 2304;
    int rem = v - ix * 2304;
    int iy = rem / 48;
    int iz = rem - iy * 48;
    float gx = origin[b * 3 + 0] + lattice[b * 9 + 0] * (ix * (1.0f / 47.0f));
    float gy = origin[b * 3 + 1] + lattice[b * 9 + 4] * (iy * (1.0f / 47.0f));
    float gz = origin[b * 3 + 2] + lattice[b * 9 + 8] * (iz * (1.0f / 47.0f));
    int na = bnodes[b];
    int vswz = v_loc & 7;
    char* rowp = Ac + v_loc * 256;
    float s = 0.f;
#pragma unroll
    for (int i = 0; i < 32; i += 2) {
      float e2[2];
#pragma unroll
      for (int j = 0; j < 2; ++j) {
        int a = half * 32 + i + j;
        float dx = gx - ps[a * 3 + 0];
        float dy = gy - ps[a * 3 + 1];
        float dz = gz - ps[a * 3 + 2];
        float d = sqrtf(fmaxf(dx * dx + dy * dy + dz * dz, 1e-12f));
        float e = (a < na) ? __expf(-d) : 0.f;
        e2[j] = e;
        s += e;
      }
      int byteoff = (half * 32 + i) * 2;
      int slot = byteoff >> 4;
      *(unsigned*)(rowp + (((slot ^ vswz) << 4) | (byteoff & 15))) = pk2bf(e2[0], e2[1]);
    }
    s += __shfl_xor(s, 32);
    if (half == 0) sinv[v_loc] = 1.0f / s;
  }

  // x -> bf16 -> Ac slots 8..15 (thread: 2 channels x 16 voxels)
  {
    int cp = t >> 1;         // 0..31 -> channels 2cp, 2cp+1
    int vq = t & 1;          // 16-voxel half
    const float* xa = x + ((size_t)(b * 64 + 2 * cp)) * NV + v0 + vq * 16;
    const float* xb2 = xa + NV;
    int slot = 8 + (cp >> 2);
    int off = (cp & 3) * 4;
#pragma unroll
    for (int it = 0; it < 4; ++it) {
      float4 fa = *(const float4*)(xa + it * 4);
      float4 fb = *(const float4*)(xb2 + it * 4);
      int rbase = vq * 16 + it * 4;
#pragma unroll
      for (int j = 0; j < 4; ++j) {
        int row = rbase + j;
        float va = ((const float*)&fa)[j];
        float vb2 = ((const float*)&fb)[j];
        *(unsigned*)(Ac + row * 256 + (((slot ^ (row & 7)) << 4) | off)) = pk2bf(va, vb2);
      }
    }
  }
  __syncthreads();

  // MFMA: K 0..63 (att@u), scale by sinv, K 64..127 (x@W_x^T); Bf on demand
  f32x4 acc[2][4];
#pragma unroll
  for (int mt = 0; mt < 2; ++mt)
#pragma unroll
    for (int nt = 0; nt < 4; ++nt) acc[mt][nt] = (f32x4){0.f, 0.f, 0.f, 0.f};

  const ushort* bp = BcT + b * 8192 + lm * 128 + lg * 8;
  auto do_k = [&](int kb) {
    short8 Bfk[4], Af[2];
#pragma unroll
    for (int nt = 0; nt < 4; ++nt)
      Bfk[nt] = *(const short8*)(bp + nt * 2048 + kb * 32);
#pragma unroll
    for (int mt = 0; mt < 2; ++mt) {
      int row = mt * 16 + lm;
      Af[mt] = *(const short8*)(Ac + row * 256 + ((((kb << 2) + lg) ^ (row & 7)) << 4));
    }
#pragma unroll
    for (int mt = 0; mt < 2; ++mt)
#pragma unroll
      for (int nt = 0; nt < 4; ++nt)
        acc[mt][nt] = __builtin_amdgcn_mfma_f32_16x16x32_bf16(Af[mt], Bfk[nt], acc[mt][nt], 0, 0, 0);
  };
  do_k(0);
  do_k(1);
#pragma unroll
  for (int mt = 0; mt < 2; ++mt) {
    float4 s4 = *(const float4*)&sinv[mt * 16 + lg * 4];
#pragma unroll
    for (int nt = 0; nt < 4; ++nt) {
      acc[mt][nt][0] *= s4.x;
      acc[mt][nt][1] *= s4.y;
      acc[mt][nt][2] *= s4.z;
      acc[mt][nt][3] *= s4.w;
    }
  }
  do_k(2);
  do_k(3);

  __syncthreads();
  float bo[4];
#pragma unroll
  for (int nt = 0; nt < 4; ++nt) bo[nt] = ob[nt * 16 + lm];
#pragma unroll
  for (int mt = 0; mt < 2; ++mt)
#pragma unroll
    for (int nt = 0; nt < 4; ++nt) {
      int o = nt * 16 + lm;
      int slot = o >> 3;
      int off = (o & 7) * 2;
#pragma unroll
      for (int r = 0; r < 4; ++r) {
        int row = mt * 16 + lg * 4 + r;
        float hv = fmaxf(acc[mt][nt][r] + bo[nt], 0.f);
        *(ushort*)(Ac + row * 128 + (((slot ^ (row & 7)) << 4) | off)) = f2bf(hv);
      }
    }
  __syncthreads();
  char* dst = (char*)hbf + ((size_t)(b * NV + v0)) * 128;
#pragma unroll
  for (int k = 0; k < 4; ++k) {
    int i = t + k * 64;
    int row = i >> 3, s = i & 7;
    *(uint4*)(dst + row * 128 + s * 16) =
        *(const uint4*)(Ac + row * 128 + ((s ^ (row & 7)) << 4));
  }
}

// ---- kernel 3: MFMA wrap-conv, 32x32x16, tile (4,4,8)=128 vox, 144B rows ----
// (r14 winner, unchanged)
__global__ __launch_bounds__(256, 3) void k_conv(
    const ushort* __restrict__ hbf, const ushort* __restrict__ wbf,
    const float* __restrict__ cb, const float* __restrict__ x,
    float* __restrict__ out) {
  __shared__ __align__(16) char sm[51840];
  int t = threadIdx.x;
  int lane = t & 63, wave = t >> 6;
  int lm32 = lane & 31, lh = lane >> 5;
  int kc = wave >> 1;
  int mh = wave & 1;

  int bid = blockIdx.x;                      // 3456 = 8*432, bijective swizzle
  int sw = (bid & 7) * 432 + (bid >> 3);
  int b = sw / 864, tid = sw - b * 864;
  int xt = tid / 72, rem = tid - xt * 72, yt = rem / 6, zt = rem - yt * 6;
  int x0 = xt * 4, y0 = yt * 4, z0 = zt * 8;

  const char* hbase = (const char*)hbf + (size_t)b * NV * 128;
  const ushort* wl = wbf + kc * 2048 + lane * 8;   // [off][kc][nt][kk][lane][e]

  short8 Ba[2][2], Bb[2][2], Bc[2][2];   // [nt][kk]
#pragma unroll
  for (int nt = 0; nt < 2; ++nt)
#pragma unroll
    for (int kk = 0; kk < 2; ++kk) {
      Ba[nt][kk] = *(const short8*)(wl + nt * 1024 + kk * 512);
      Bb[nt][kk] = *(const short8*)(wl + 4096 + nt * 1024 + kk * 512);
    }

  // stage halo: 360 rows (row = hx*60 + hy*10 + hz) x 8 slots, 144B-pad rows
#pragma unroll
  for (int k = 0; k < 12; ++k) {
    int c = t + k * 256;
    if (c < 2880) {
      int r = c >> 3, j = c & 7;
      int hx = r / 60, rr = r - hx * 60, hy = rr / 10, hz = rr - hy * 10;
      int gx = x0 + hx - 1; gx += (gx < 0) ? 48 : 0; gx -= (gx >= 48) ? 48 : 0;
      int gy = y0 + hy - 1; gy += (gy < 0) ? 48 : 0; gy -= (gy >= 48) ? 48 : 0;
      int gz = z0 + hz - 1; gz += (gz < 0) ? 48 : 0; gz -= (gz >= 48) ? 48 : 0;
      uint4 v = *(const uint4*)(hbase + (size_t)((gx * 2304 + gy * 48 + gz) * 128 + j * 16));
      *(uint4*)(sm + r * 144 + j * 16) = v;
    }
  }

  int yl = lm32 >> 3, zl = lm32 & 7;
  char* Abase[2];
#pragma unroll
  for (int mt = 0; mt < 2; ++mt)
    Abase[mt] = sm + (((mh * 2 + mt) * 60 + yl * 10 + zl) * 144) + (kc * 4 + lh) * 16;

  f32x16 acc[2][2];
#pragma unroll
  for (int i = 0; i < 2; ++i)
#pragma unroll
    for (int j = 0; j < 2; ++j)
#pragma unroll
      for (int q = 0; q < 16; ++q) acc[i][j][q] = 0.f;

  __syncthreads();

#define STEPC(o, Bcur, Bpre) { \
    if ((o) + 2 < 27) { \
      const ushort* p = wl + ((o) + 2) * 4096; \
      _Pragma("unroll") \
      for (int nt = 0; nt < 2; ++nt) \
        _Pragma("unroll") \
        for (int kk = 0; kk < 2; ++kk) \
          Bpre[nt][kk] = *(const short8*)(p + nt * 1024 + kk * 512); \
    } \
    { \
      const int dxo = (o) / 9, dyzo = (o) - dxo * 9, dyo = dyzo / 3, dzo = dyzo - dyo * 3; \
      const int aimm = (dxo * 60 + dyo * 10 + dzo) * 144; \
      short8 Af[2][2]; \
      _Pragma("unroll") \
      for (int mt = 0; mt < 2; ++mt) \
        _Pragma("unroll") \
        for (int kk = 0; kk < 2; ++kk) \
          Af[mt][kk] = *(const short8*)(Abase[mt] + aimm + kk * 32); \
      __builtin_amdgcn_sched_barrier(0); \
      __builtin_amdgcn_s_setprio(1); \
      _Pragma("unroll") \
      for (int kk = 0; kk < 2; ++kk) \
        _Pragma("unroll") \
        for (int mt = 0; mt < 2; ++mt) \
          _Pragma("unroll") \
          for (int nt = 0; nt < 2; ++nt) \
            acc[mt][nt] = __builtin_amdgcn_mfma_f32_32x32x16_bf16(Af[mt][kk], Bcur[nt][kk], acc[mt][nt], 0, 0, 0); \
      __builtin_amdgcn_s_setprio(0); \
      __builtin_amdgcn_sched_barrier(0); \
    } \
  }

  STEPC(0, Ba, Bc)  STEPC(1, Bb, Ba)  STEPC(2, Bc, Bb)
  STEPC(3, Ba, Bc)  STEPC(4, Bb, Ba)  STEPC(5, Bc, Bb)
  STEPC(6, Ba, Bc)  STEPC(7, Bb, Ba)  STEPC(8, Bc, Bb)
  STEPC(9, Ba, Bc)  STEPC(10, Bb, Ba) STEPC(11, Bc, Bb)
  STEPC(12, Ba, Bc) STEPC(13, Bb, Ba) STEPC(14, Bc, Bb)
  STEPC(15, Ba, Bc) STEPC(16, Bb, Ba) STEPC(17, Bc, Bb)
  STEPC(18, Ba, Bc) STEPC(19, Bb, Ba) STEPC(20, Bc, Bb)
  STEPC(21, Ba, Bc) STEPC(22, Bb, Ba) STEPC(23, Bc, Bb)
  STEPC(24, Ba, Bc) STEPC(25, Bb, Ba) STEPC(26, Bc, Bb)
#undef STEPC

  // epilogue x-residual hoist
  const float* xb = x + (size_t)b * NC * NV;
  float* obp = out + (size_t)b * NC * NV;
  float4 xr4[8];
  size_t gaddr[8];
#pragma unroll
  for (int k = 0; k < 8; ++k) {
    int i = t + k * 256;
    int co = i >> 5, vq = i & 31;
    int v = vq * 4;
    int xl = v >> 5, rm = v & 31, yl2 = rm >> 3, zl2 = rm & 7;
    size_t g = (size_t)co * NV + (x0 + xl) * 2304 + (y0 + yl2) * 48 + (z0 + zl2);
    gaddr[k] = g;
    xr4[k] = *(const float4*)(xb + g);
  }

  __syncthreads();
  float* red = (float*)sm;
  if (kc == 1) {
#pragma unroll
    for (int mt = 0; mt < 2; ++mt)
#pragma unroll
      for (int nt = 0; nt < 2; ++nt) {
        int co = nt * 32 + lm32;
#pragma unroll
        for (int q = 0; q < 4; ++q) {
          int vox = mh * 64 + mt * 32 + q * 8 + lh * 4;
          *(float4*)&red[co * 132 + vox] = (float4){acc[mt][nt][q * 4 + 0], acc[mt][nt][q * 4 + 1],
                                                    acc[mt][nt][q * 4 + 2], acc[mt][nt][q * 4 + 3]};
        }
      }
  }
  __syncthreads();
  if (kc == 0) {
#pragma unroll
    for (int nt = 0; nt < 2; ++nt) {
      int co = nt * 32 + lm32;
      float bo = cb[co];
#pragma unroll
      for (int mt = 0; mt < 2; ++mt)
#pragma unroll
        for (int q = 0; q < 4; ++q) {
          int vox = mh * 64 + mt * 32 + q * 8 + lh * 4;
          float4 p = *(const float4*)&red[co * 132 + vox];
          float4 r;
          r.x = fmaxf(acc[mt][nt][q * 4 + 0] + p.x + bo, 0.f);
          r.y = fmaxf(acc[mt][nt][q * 4 + 1] + p.y + bo, 0.f);
          r.z = fmaxf(acc[mt][nt][q * 4 + 2] + p.z + bo, 0.f);
          r.w = fmaxf(acc[mt][nt][q * 4 + 3] + p.w + bo, 0.f);
          *(float4*)&red[co * 132 + vox] = r;
        }
    }
  }
  __syncthreads();
#pragma unroll
  for (int k = 0; k < 8; ++k) {
    int i = t + k * 256;
    int co = i >> 5, vq = i & 31;
    float4 rv = *(const float4*)&red[co * 132 + vq * 4];
    float4 o4;
    o4.x = rv.x + xr4[k].x;
    o4.y = rv.y + xr4[k].y;
    o4.z = rv.z + xr4[k].z;
    o4.w = rv.w + xr4[k].w;
    *(float4*)(obp + gaddr[k]) = o4;
  }
}

extern "C" void kernel_launch(void* const* d_in, const int* in_sizes, int n_in,
                              void* d_out, int out_size, void* d_ws, size_t ws_size,
                              hipStream_t stream) {
  const float* x = (const float*)d_in[0];
  const float* me = (const float*)d_in[1];
  const float* pos = (const float*)d_in[2];
  const float* origin = (const float*)d_in[3];
  const float* lattice = (const float*)d_in[4];
  const int* bn = (const int*)d_in[5];
  const float* vw = (const float*)d_in[6];
  const float* vb = (const float*)d_in[7];
  const float* ow = (const float*)d_in[8];
  const float* ob = (const float*)d_in[9];
  const float* cw = (const float*)d_in[10];
  const float* cbias = (const float*)d_in[11];
  float* outp = (float*)d_out;

  ushort* BcT = (ushort*)d_ws;                              // 64 KB
  ushort* wbf = (ushort*)((char*)d_ws + 65536);             // 216 KB (frag-major 32x32)
  ushort* hbf = (ushort*)((char*)d_ws + 65536 + 221184);    // 56.6 MB
  float* vmat = (float*)hbf;   // scratch inside hbf; consumed before att2 writes hbf

  k_vm<<<64, 256, 0, stream>>>(me, vw, vb, vmat);
  k_bct<<<32, 256, 0, stream>>>(ow, vmat, BcT);
  k_wt<<<(27 * 64 * 64 + 255) / 256, 256, 0, stream>>>(cw, wbf);
  k_att2<<<dim3(NV / 32, NB), 64, 0, stream>>>(x, pos, origin, lattice, bn, ob, BcT, hbf);
  k_conv<<<3456, 256, 0, stream>>>(hbf, wbf, cbias, x, outp);
}

// Round 16
// 183.422 us; speedup vs baseline: 1.0033x; 1.0033x over previous
//
#include <hip/hip_runtime.h>

#define NB 4
#define NC 64
#define NV (48*48*48)
#define NA 64
#define NE 128

typedef __attribute__((ext_vector_type(8))) short short8;
typedef __attribute__((ext_vector_type(4))) float f32x4;
typedef __attribute__((ext_vector_type(16))) float f32x16;

static __device__ __forceinline__ ushort f2bf(float f) {
  unsigned u = __float_as_uint(f);
  unsigned r = (u + 0x7FFF + ((u >> 16) & 1)) >> 16;
  return (ushort)r;
}
static __device__ __forceinline__ unsigned pk2bf(float lo, float hi) {
  return (unsigned)f2bf(lo) | ((unsigned)f2bf(hi) << 16);
}

// ---- kernel 1a: vmat[b][a][c] = me @ v_w^T + v_b  (64 blocks, parallel) ----
__global__ __launch_bounds__(256) void k_vm(
    const float* __restrict__ me, const float* __restrict__ vw,
    const float* __restrict__ vb, float* __restrict__ vmat) {
  int blk = blockIdx.x;
  int b = blk >> 4, aq = blk & 15;
  int t = threadIdx.x;
  int a = aq * 4 + (t >> 6);
  int c = t & 63;
  const float* mp = me + (size_t)(b * 64 + a) * 128;
  const float* wp = vw + (size_t)c * 128;
  float acc = vb[c];
#pragma unroll 8
  for (int e = 0; e < 128; e += 4) {
    float4 m4 = *(const float4*)(mp + e);
    float4 w4 = *(const float4*)(wp + e);
    acc += m4.x * w4.x + m4.y * w4.y + m4.z * w4.z + m4.w * w4.w;
  }
  vmat[b * 4096 + a * 64 + c] = acc;
}

// ---- kernel 1c: BcT[b][o][128]: k<64 -> u[k][o]=VM@W_v^T, k>=64 -> W_x -----
__global__ __launch_bounds__(256) void k_bct(
    const float* __restrict__ ow, const float* __restrict__ vmat,
    ushort* __restrict__ BcT) {
  __shared__ float VM[64 * 68];
  __shared__ float WV[8 * 68];
  int blk = blockIdx.x;
  int b = blk >> 3, og = blk & 7;
  int t = threadIdx.x;
  for (int i = t; i < 4096; i += 256)
    VM[(i >> 6) * 68 + (i & 63)] = vmat[b * 4096 + i];
  for (int i = t; i < 512; i += 256)
    WV[(i >> 6) * 68 + (i & 63)] = ow[(og * 8 + (i >> 6)) * 128 + 64 + (i & 63)];
  __syncthreads();
  int ol = t >> 5;
  int a0 = (t & 31) * 2;
  int o = og * 8 + ol;
#pragma unroll
  for (int p = 0; p < 2; ++p) {
    int a = a0 + p;
    float acc = 0.f;
#pragma unroll 8
    for (int c = 0; c < 64; c += 4) {
      float4 v4 = *(const float4*)&VM[a * 68 + c];
      float4 w4 = *(const float4*)&WV[ol * 68 + c];
      acc += v4.x * w4.x + v4.y * w4.y + v4.z * w4.z + v4.w * w4.w;
    }
    BcT[b * 8192 + o * 128 + a] = f2bf(acc);
  }
#pragma unroll
  for (int p = 0; p < 2; ++p) {
    int i = t * 2 + p;
    int ol2 = i >> 6, ci = i & 63;
    int o2 = og * 8 + ol2;
    BcT[b * 8192 + o2 * 128 + 64 + ci] = f2bf(ow[o2 * 128 + ci]);
  }
}

// --- kernel 1b: conv weights -> bf16 frag-major for 32x32x16 MFMA ------------
__global__ void k_wt(const float* __restrict__ cw, ushort* __restrict__ wbf) {
  int idx = blockIdx.x * 256 + threadIdx.x;
  if (idx >= 27 * 64 * 64) return;
  int off = idx >> 12, r = idx & 4095;
  int kcw = r >> 11, r2 = r & 2047;
  int nt = r2 >> 10, r3 = r2 & 1023;
  int kk = r3 >> 9, r4 = r3 & 511;
  int ln = r4 >> 3, e = r4 & 7;
  int co = nt * 32 + (ln & 31);
  int ci = kcw * 32 + kk * 16 + (ln >> 5) * 8 + e;
  wbf[idx] = f2bf(cw[(co * 64 + ci) * 27 + off]);
}

// -------- kernel 2: 1-WAVE blocks (32 vox), barrier-cheap, on-demand Bf ------
__global__ __launch_bounds__(64) void k_att2(
    const float* __restrict__ x, const float* __restrict__ pos,
    const float* __restrict__ origin, const float* __restrict__ lattice,
    const int* __restrict__ bnodes, const float* __restrict__ ob,
    const ushort* __restrict__ BcT, ushort* __restrict__ hbf) {
  __shared__ __align__(16) char Ac[8192];    // [32 rows][256 B], slot^(row&7)
  __shared__ float ps[192];
  __shared__ float sinv[32];
  int t = threadIdx.x;                       // 0..63 (one wave)
  int b = blockIdx.y;
  int v0 = blockIdx.x * 32;
  int lm = t & 15, lg = t >> 4;              // lg 0..3

  for (int i = t; i < 192; i += 64) ps[i] = pos[b * 192 + i];
  __syncthreads();

  // dist + exp -> Ac slots 0..7 (unnormalized), sinv
  {
    int v_loc = t & 31;
    int half = t >> 5;
    int v = v0 + v_loc;
    int ix = v / 2304;
    int rem = v - ix * 2304;
    int iy = rem / 48;
    int iz = rem - iy * 48;
    float gx = origin[b * 3 + 0] + lattice[b * 9 + 0] * (ix * (1.0f / 47.0f));
    float gy = origin[b * 3 + 1] + lattice[b * 9 + 4] * (iy * (1.0f / 47.0f));
    float gz = origin[b * 3 + 2] + lattice[b * 9 + 8] * (iz * (1.0f / 47.0f));
    int na = bnodes[b];
    int vswz = v_loc & 7;
    char* rowp = Ac + v_loc * 256;
    float s = 0.f;
#pragma unroll
    for (int i = 0; i < 32; i += 2) {
      float e2[2];
#pragma unroll
      for (int j = 0; j < 2; ++j) {
        int a = half * 32 + i + j;
        float dx = gx - ps[a * 3 + 0];
        float dy = gy - ps[a * 3 + 1];
        float dz = gz - ps[a * 3 + 2];
        float d = sqrtf(fmaxf(dx * dx + dy * dy + dz * dz, 1e-12f));
        float e = (a < na) ? __expf(-d) : 0.f;
        e2[j] = e;
        s += e;
      }
      int byteoff = (half * 32 + i) * 2;
      int slot = byteoff >> 4;
      *(unsigned*)(rowp + (((slot ^ vswz) << 4) | (byteoff & 15))) = pk2bf(e2[0], e2[1]);
    }
    s += __shfl_xor(s, 32);
    if (half == 0) sinv[v_loc] = 1.0f / s;
  }

  // x -> bf16 -> Ac slots 8..15 (thread: 2 channels x 16 voxels)
  {
    int cp = t >> 1;
    int vq = t & 1;
    const float* xa = x + ((size_t)(b * 64 + 2 * cp)) * NV + v0 + vq * 16;
    const float* xb2 = xa + NV;
    int slot = 8 + (cp >> 2);
    int off = (cp & 3) * 4;
#pragma unroll
    for (int it = 0; it < 4; ++it) {
      float4 fa = *(const float4*)(xa + it * 4);
      float4 fb = *(const float4*)(xb2 + it * 4);
      int rbase = vq * 16 + it * 4;
#pragma unroll
      for (int j = 0; j < 4; ++j) {
        int row = rbase + j;
        float va = ((const float*)&fa)[j];
        float vb2 = ((const float*)&fb)[j];
        *(unsigned*)(Ac + row * 256 + (((slot ^ (row & 7)) << 4) | off)) = pk2bf(va, vb2);
      }
    }
  }
  __syncthreads();

  f32x4 acc[2][4];
#pragma unroll
  for (int mt = 0; mt < 2; ++mt)
#pragma unroll
    for (int nt = 0; nt < 4; ++nt) acc[mt][nt] = (f32x4){0.f, 0.f, 0.f, 0.f};

  const ushort* bp = BcT + b * 8192 + lm * 128 + lg * 8;
  auto do_k = [&](int kb) {
    short8 Bfk[4], Af[2];
#pragma unroll
    for (int nt = 0; nt < 4; ++nt)
      Bfk[nt] = *(const short8*)(bp + nt * 2048 + kb * 32);
#pragma unroll
    for (int mt = 0; mt < 2; ++mt) {
      int row = mt * 16 + lm;
      Af[mt] = *(const short8*)(Ac + row * 256 + ((((kb << 2) + lg) ^ (row & 7)) << 4));
    }
#pragma unroll
    for (int mt = 0; mt < 2; ++mt)
#pragma unroll
      for (int nt = 0; nt < 4; ++nt)
        acc[mt][nt] = __builtin_amdgcn_mfma_f32_16x16x32_bf16(Af[mt], Bfk[nt], acc[mt][nt], 0, 0, 0);
  };
  do_k(0);
  do_k(1);
#pragma unroll
  for (int mt = 0; mt < 2; ++mt) {
    float4 s4 = *(const float4*)&sinv[mt * 16 + lg * 4];
#pragma unroll
    for (int nt = 0; nt < 4; ++nt) {
      acc[mt][nt][0] *= s4.x;
      acc[mt][nt][1] *= s4.y;
      acc[mt][nt][2] *= s4.z;
      acc[mt][nt][3] *= s4.w;
    }
  }
  do_k(2);
  do_k(3);

  __syncthreads();
  float bo[4];
#pragma unroll
  for (int nt = 0; nt < 4; ++nt) bo[nt] = ob[nt * 16 + lm];
#pragma unroll
  for (int mt = 0; mt < 2; ++mt)
#pragma unroll
    for (int nt = 0; nt < 4; ++nt) {
      int o = nt * 16 + lm;
      int slot = o >> 3;
      int off = (o & 7) * 2;
#pragma unroll
      for (int r = 0; r < 4; ++r) {
        int row = mt * 16 + lg * 4 + r;
        float hv = fmaxf(acc[mt][nt][r] + bo[nt], 0.f);
        *(ushort*)(Ac + row * 128 + (((slot ^ (row & 7)) << 4) | off)) = f2bf(hv);
      }
    }
  __syncthreads();
  char* dst = (char*)hbf + ((size_t)(b * NV + v0)) * 128;
#pragma unroll
  for (int k = 0; k < 4; ++k) {
    int i = t + k * 64;
    int row = i >> 3, s = i & 7;
    *(uint4*)(dst + row * 128 + s * 16) =
        *(const uint4*)(Ac + row * 128 + ((s ^ (row & 7)) << 4));
  }
}

// ---- kernel 3: MFMA wrap-conv, 32x32x16, tile (4,4,8), + drift-bound sync ---
// r14 winner + raw s_barrier every 3 offsets: bounds wave drift to <=3 offsets
// (24 KB B) so same-kc waves share B-fragments through the 32 KB per-CU L1
// (halves B L2 traffic). Raw barrier = no waitcnt drain (B prefetch goes to
// registers; no cross-wave hazard).
__global__ __launch_bounds__(256, 3) void k_conv(
    const ushort* __restrict__ hbf, const ushort* __restrict__ wbf,
    const float* __restrict__ cb, const float* __restrict__ x,
    float* __restrict__ out) {
  __shared__ __align__(16) char sm[51840];
  int t = threadIdx.x;
  int lane = t & 63, wave = t >> 6;
  int lm32 = lane & 31, lh = lane >> 5;
  int kc = wave >> 1;
  int mh = wave & 1;

  int bid = blockIdx.x;                      // 3456 = 8*432, bijective swizzle
  int sw = (bid & 7) * 432 + (bid >> 3);
  int b = sw / 864, tid = sw - b * 864;
  int xt = tid / 72, rem = tid - xt * 72, yt = rem / 6, zt = rem - yt * 6;
  int x0 = xt * 4, y0 = yt * 4, z0 = zt * 8;

  const char* hbase = (const char*)hbf + (size_t)b * NV * 128;
  const ushort* wl = wbf + kc * 2048 + lane * 8;   // [off][kc][nt][kk][lane][e]

  short8 Ba[2][2], Bb[2][2], Bc[2][2];   // [nt][kk]
#pragma unroll
  for (int nt = 0; nt < 2; ++nt)
#pragma unroll
    for (int kk = 0; kk < 2; ++kk) {
      Ba[nt][kk] = *(const short8*)(wl + nt * 1024 + kk * 512);
      Bb[nt][kk] = *(const short8*)(wl + 4096 + nt * 1024 + kk * 512);
    }

  // stage halo: 360 rows (row = hx*60 + hy*10 + hz) x 8 slots, 144B-pad rows
#pragma unroll
  for (int k = 0; k < 12; ++k) {
    int c = t + k * 256;
    if (c < 2880) {
      int r = c >> 3, j = c & 7;
      int hx = r / 60, rr = r - hx * 60, hy = rr / 10, hz = rr - hy * 10;
      int gx = x0 + hx - 1; gx += (gx < 0) ? 48 : 0; gx -= (gx >= 48) ? 48 : 0;
      int gy = y0 + hy - 1; gy += (gy < 0) ? 48 : 0; gy -= (gy >= 48) ? 48 : 0;
      int gz = z0 + hz - 1; gz += (gz < 0) ? 48 : 0; gz -= (gz >= 48) ? 48 : 0;
      uint4 v = *(const uint4*)(hbase + (size_t)((gx * 2304 + gy * 48 + gz) * 128 + j * 16));
      *(uint4*)(sm + r * 144 + j * 16) = v;
    }
  }

  int yl = lm32 >> 3, zl = lm32 & 7;
  char* Abase[2];
#pragma unroll
  for (int mt = 0; mt < 2; ++mt)
    Abase[mt] = sm + (((mh * 2 + mt) * 60 + yl * 10 + zl) * 144) + (kc * 4 + lh) * 16;

  f32x16 acc[2][2];
#pragma unroll
  for (int i = 0; i < 2; ++i)
#pragma unroll
    for (int j = 0; j < 2; ++j)
#pragma unroll
      for (int q = 0; q < 16; ++q) acc[i][j][q] = 0.f;

  __syncthreads();

#define STEPC(o, Bcur, Bpre) { \
    if ((o) + 2 < 27) { \
      const ushort* p = wl + ((o) + 2) * 4096; \
      _Pragma("unroll") \
      for (int nt = 0; nt < 2; ++nt) \
        _Pragma("unroll") \
        for (int kk = 0; kk < 2; ++kk) \
          Bpre[nt][kk] = *(const short8*)(p + nt * 1024 + kk * 512); \
    } \
    { \
      const int dxo = (o) / 9, dyzo = (o) - dxo * 9, dyo = dyzo / 3, dzo = dyzo - dyo * 3; \
      const int aimm = (dxo * 60 + dyo * 10 + dzo) * 144; \
      short8 Af[2][2]; \
      _Pragma("unroll") \
      for (int mt = 0; mt < 2; ++mt) \
        _Pragma("unroll") \
        for (int kk = 0; kk < 2; ++kk) \
          Af[mt][kk] = *(const short8*)(Abase[mt] + aimm + kk * 32); \
      __builtin_amdgcn_sched_barrier(0); \
      __builtin_amdgcn_s_setprio(1); \
      _Pragma("unroll") \
      for (int kk = 0; kk < 2; ++kk) \
        _Pragma("unroll") \
        for (int mt = 0; mt < 2; ++mt) \
          _Pragma("unroll") \
          for (int nt = 0; nt < 2; ++nt) \
            acc[mt][nt] = __builtin_amdgcn_mfma_f32_32x32x16_bf16(Af[mt][kk], Bcur[nt][kk], acc[mt][nt], 0, 0, 0); \
      __builtin_amdgcn_s_setprio(0); \
      __builtin_amdgcn_sched_barrier(0); \
    } \
  }

  STEPC(0, Ba, Bc)  STEPC(1, Bb, Ba)  STEPC(2, Bc, Bb)
  __builtin_amdgcn_s_barrier();
  STEPC(3, Ba, Bc)  STEPC(4, Bb, Ba)  STEPC(5, Bc, Bb)
  __builtin_amdgcn_s_barrier();
  STEPC(6, Ba, Bc)  STEPC(7, Bb, Ba)  STEPC(8, Bc, Bb)
  __builtin_amdgcn_s_barrier();
  STEPC(9, Ba, Bc)  STEPC(10, Bb, Ba) STEPC(11, Bc, Bb)
  __builtin_amdgcn_s_barrier();
  STEPC(12, Ba, Bc) STEPC(13, Bb, Ba) STEPC(14, Bc, Bb)
  __builtin_amdgcn_s_barrier();
  STEPC(15, Ba, Bc) STEPC(16, Bb, Ba) STEPC(17, Bc, Bb)
  __builtin_amdgcn_s_barrier();
  STEPC(18, Ba, Bc) STEPC(19, Bb, Ba) STEPC(20, Bc, Bb)
  __builtin_amdgcn_s_barrier();
  STEPC(21, Ba, Bc) STEPC(22, Bb, Ba) STEPC(23, Bc, Bb)
  __builtin_amdgcn_s_barrier();
  STEPC(24, Ba, Bc) STEPC(25, Bb, Ba) STEPC(26, Bc, Bb)
#undef STEPC

  // epilogue x-residual hoist
  const float* xb = x + (size_t)b * NC * NV;
  float* obp = out + (size_t)b * NC * NV;
  float4 xr4[8];
  size_t gaddr[8];
#pragma unroll
  for (int k = 0; k < 8; ++k) {
    int i = t + k * 256;
    int co = i >> 5, vq = i & 31;
    int v = vq * 4;
    int xl = v >> 5, rm = v & 31, yl2 = rm >> 3, zl2 = rm & 7;
    size_t g = (size_t)co * NV + (x0 + xl) * 2304 + (y0 + yl2) * 48 + (z0 + zl2);
    gaddr[k] = g;
    xr4[k] = *(const float4*)(xb + g);
  }

  __syncthreads();
  float* red = (float*)sm;
  if (kc == 1) {
#pragma unroll
    for (int mt = 0; mt < 2; ++mt)
#pragma unroll
      for (int nt = 0; nt < 2; ++nt) {
        int co = nt * 32 + lm32;
#pragma unroll
        for (int q = 0; q < 4; ++q) {
          int vox = mh * 64 + mt * 32 + q * 8 + lh * 4;
          *(float4*)&red[co * 132 + vox] = (float4){acc[mt][nt][q * 4 + 0], acc[mt][nt][q * 4 + 1],
                                                    acc[mt][nt][q * 4 + 2], acc[mt][nt][q * 4 + 3]};
        }
      }
  }
  __syncthreads();
  if (kc == 0) {
#pragma unroll
    for (int nt = 0; nt < 2; ++nt) {
      int co = nt * 32 + lm32;
      float bo = cb[co];
#pragma unroll
      for (int mt = 0; mt < 2; ++mt)
#pragma unroll
        for (int q = 0; q < 4; ++q) {
          int vox = mh * 64 + mt * 32 + q * 8 + lh * 4;
          float4 p = *(const float4*)&red[co * 132 + vox];
          float4 r;
          r.x = fmaxf(acc[mt][nt][q * 4 + 0] + p.x + bo, 0.f);
          r.y = fmaxf(acc[mt][nt][q * 4 + 1] + p.y + bo, 0.f);
          r.z = fmaxf(acc[mt][nt][q * 4 + 2] + p.z + bo, 0.f);
          r.w = fmaxf(acc[mt][nt][q * 4 + 3] + p.w + bo, 0.f);
          *(float4*)&red[co * 132 + vox] = r;
        }
    }
  }
  __syncthreads();
#pragma unroll
  for (int k = 0; k < 8; ++k) {
    int i = t + k * 256;
    int co = i >> 5, vq = i & 31;
    float4 rv = *(const float4*)&red[co * 132 + vq * 4];
    float4 o4;
    o4.x = rv.x + xr4[k].x;
    o4.y = rv.y + xr4[k].y;
    o4.z = rv.z + xr4[k].z;
    o4.w = rv.w + xr4[k].w;
    *(float4*)(obp + gaddr[k]) = o4;
  }
}

extern "C" void kernel_launch(void* const* d_in, const int* in_sizes, int n_in,
                              void* d_out, int out_size, void* d_ws, size_t ws_size,
                              hipStream_t stream) {
  const float* x = (const float*)d_in[0];
  const float* me = (const float*)d_in[1];
  const float* pos = (const float*)d_in[2];
  const float* origin = (const float*)d_in[3];
  const float* lattice = (const float*)d_in[4];
  const int* bn = (const int*)d_in[5];
  const float* vw = (const float*)d_in[6];
  const float* vb = (const float*)d_in[7];
  const float* ow = (const float*)d_in[8];
  const float* ob = (const float*)d_in[9];
  const float* cw = (const float*)d_in[10];
  const float* cbias = (const float*)d_in[11];
  float* outp = (float*)d_out;

  ushort* BcT = (ushort*)d_ws;                              // 64 KB
  ushort* wbf = (ushort*)((char*)d_ws + 65536);             // 216 KB (frag-major 32x32)
  ushort* hbf = (ushort*)((char*)d_ws + 65536 + 221184);    // 56.6 MB
  float* vmat = (float*)hbf;   // scratch inside hbf; consumed before att2 writes hbf

  k_vm<<<64, 256, 0, stream>>>(me, vw, vb, vmat);
  k_bct<<<32, 256, 0, stream>>>(ow, vmat, BcT);
  k_wt<<<(27 * 64 * 64 + 255) / 256, 256, 0, stream>>>(cw, wbf);
  k_att2<<<dim3(NV / 32, NB), 64, 0, stream>>>(x, pos, origin, lattice, bn, ob, BcT, hbf);
  k_conv<<<3456, 256, 0, stream>>>(hbf, wbf, cbias, x, outp);
}

// Round 17
// 178.778 us; speedup vs baseline: 1.0294x; 1.0260x over previous
//
#include <hip/hip_runtime.h>

#define NB 4
#define NC 64
#define NV (48*48*48)
#define NA 64
#define NE 128

typedef __attribute__((ext_vector_type(8))) short short8;
typedef __attribute__((ext_vector_type(4))) float f32x4;
typedef __attribute__((ext_vector_type(16))) float f32x16;

static __device__ __forceinline__ ushort f2bf(float f) {
  unsigned u = __float_as_uint(f);
  unsigned r = (u + 0x7FFF + ((u >> 16) & 1)) >> 16;
  return (ushort)r;
}
static __device__ __forceinline__ unsigned pk2bf(float lo, float hi) {
  return (unsigned)f2bf(lo) | ((unsigned)f2bf(hi) << 16);
}

// ---- kernel 1a: vmat[b][a][c] = me @ v_w^T + v_b  (64 blocks, parallel) ----
__global__ __launch_bounds__(256) void k_vm(
    const float* __restrict__ me, const float* __restrict__ vw,
    const float* __restrict__ vb, float* __restrict__ vmat) {
  int blk = blockIdx.x;
  int b = blk >> 4, aq = blk & 15;
  int t = threadIdx.x;
  int a = aq * 4 + (t >> 6);
  int c = t & 63;
  const float* mp = me + (size_t)(b * 64 + a) * 128;
  const float* wp = vw + (size_t)c * 128;
  float acc = vb[c];
#pragma unroll 8
  for (int e = 0; e < 128; e += 4) {
    float4 m4 = *(const float4*)(mp + e);
    float4 w4 = *(const float4*)(wp + e);
    acc += m4.x * w4.x + m4.y * w4.y + m4.z * w4.z + m4.w * w4.w;
  }
  vmat[b * 4096 + a * 64 + c] = acc;
}

// ---- kernel 1c: BcT[b][o][128]: k<64 -> u[k][o]=VM@W_v^T, k>=64 -> W_x -----
__global__ __launch_bounds__(256) void k_bct(
    const float* __restrict__ ow, const float* __restrict__ vmat,
    ushort* __restrict__ BcT) {
  __shared__ float VM[64 * 68];
  __shared__ float WV[8 * 68];
  int blk = blockIdx.x;
  int b = blk >> 3, og = blk & 7;
  int t = threadIdx.x;
  for (int i = t; i < 4096; i += 256)
    VM[(i >> 6) * 68 + (i & 63)] = vmat[b * 4096 + i];
  for (int i = t; i < 512; i += 256)
    WV[(i >> 6) * 68 + (i & 63)] = ow[(og * 8 + (i >> 6)) * 128 + 64 + (i & 63)];
  __syncthreads();
  int ol = t >> 5;
  int a0 = (t & 31) * 2;
  int o = og * 8 + ol;
#pragma unroll
  for (int p = 0; p < 2; ++p) {
    int a = a0 + p;
    float acc = 0.f;
#pragma unroll 8
    for (int c = 0; c < 64; c += 4) {
      float4 v4 = *(const float4*)&VM[a * 68 + c];
      float4 w4 = *(const float4*)&WV[ol * 68 + c];
      acc += v4.x * w4.x + v4.y * w4.y + v4.z * w4.z + v4.w * w4.w;
    }
    BcT[b * 8192 + o * 128 + a] = f2bf(acc);
  }
#pragma unroll
  for (int p = 0; p < 2; ++p) {
    int i = t * 2 + p;
    int ol2 = i >> 6, ci = i & 63;
    int o2 = og * 8 + ol2;
    BcT[b * 8192 + o2 * 128 + 64 + ci] = f2bf(ow[o2 * 128 + ci]);
  }
}

// --- kernel 1b: conv weights -> bf16 frag-major for 32x32x16 MFMA ------------
__global__ void k_wt(const float* __restrict__ cw, ushort* __restrict__ wbf) {
  int idx = blockIdx.x * 256 + threadIdx.x;
  if (idx >= 27 * 64 * 64) return;
  int off = idx >> 12, r = idx & 4095;
  int kcw = r >> 11, r2 = r & 2047;
  int nt = r2 >> 10, r3 = r2 & 1023;
  int kk = r3 >> 9, r4 = r3 & 511;
  int ln = r4 >> 3, e = r4 & 7;
  int co = nt * 32 + (ln & 31);
  int ci = kcw * 32 + kk * 16 + (ln >> 5) * 8 + e;
  wbf[idx] = f2bf(cw[(co * 64 + ci) * 27 + off]);
}

// -------- kernel 2: 1-WAVE blocks (32 vox), barrier-cheap, on-demand Bf ------
__global__ __launch_bounds__(64) void k_att2(
    const float* __restrict__ x, const float* __restrict__ pos,
    const float* __restrict__ origin, const float* __restrict__ lattice,
    const int* __restrict__ bnodes, const float* __restrict__ ob,
    const ushort* __restrict__ BcT, ushort* __restrict__ hbf) {
  __shared__ __align__(16) char Ac[8192];    // [32 rows][256 B], slot^(row&7)
  __shared__ float ps[192];
  __shared__ float sinv[32];
  int t = threadIdx.x;                       // 0..63 (one wave)
  int b = blockIdx.y;
  int v0 = blockIdx.x * 32;
  int lm = t & 15, lg = t >> 4;              // lg 0..3

  for (int i = t; i < 192; i += 64) ps[i] = pos[b * 192 + i];
  __syncthreads();

  // dist + exp -> Ac slots 0..7 (unnormalized), sinv
  {
    int v_loc = t & 31;
    int half = t >> 5;
    int v = v0 + v_loc;
    int ix = v / 2304;
    int rem = v - ix * 2304;
    int iy = rem / 48;
    int iz = rem - iy * 48;
    float gx = origin[b * 3 + 0] + lattice[b * 9 + 0] * (ix * (1.0f / 47.0f));
    float gy = origin[b * 3 + 1] + lattice[b * 9 + 4] * (iy * (1.0f / 47.0f));
    float gz = origin[b * 3 + 2] + lattice[b * 9 + 8] * (iz * (1.0f / 47.0f));
    int na = bnodes[b];
    int vswz = v_loc & 7;
    char* rowp = Ac + v_loc * 256;
    float s = 0.f;
#pragma unroll
    for (int i = 0; i < 32; i += 2) {
      float e2[2];
#pragma unroll
      for (int j = 0; j < 2; ++j) {
        int a = half * 32 + i + j;
        float dx = gx - ps[a * 3 + 0];
        float dy = gy - ps[a * 3 + 1];
        float dz = gz - ps[a * 3 + 2];
        float d = sqrtf(fmaxf(dx * dx + dy * dy + dz * dz, 1e-12f));
        float e = (a < na) ? __expf(-d) : 0.f;
        e2[j] = e;
        s += e;
      }
      int byteoff = (half * 32 + i) * 2;
      int slot = byteoff >> 4;
      *(unsigned*)(rowp + (((slot ^ vswz) << 4) | (byteoff & 15))) = pk2bf(e2[0], e2[1]);
    }
    s += __shfl_xor(s, 32);
    if (half == 0) sinv[v_loc] = 1.0f / s;
  }

  // x -> bf16 -> Ac slots 8..15 (thread: 2 channels x 16 voxels)
  {
    int cp = t >> 1;
    int vq = t & 1;
    const float* xa = x + ((size_t)(b * 64 + 2 * cp)) * NV + v0 + vq * 16;
    const float* xb2 = xa + NV;
    int slot = 8 + (cp >> 2);
    int off = (cp & 3) * 4;
#pragma unroll
    for (int it = 0; it < 4; ++it) {
      float4 fa = *(const float4*)(xa + it * 4);
      float4 fb = *(const float4*)(xb2 + it * 4);
      int rbase = vq * 16 + it * 4;
#pragma unroll
      for (int j = 0; j < 4; ++j) {
        int row = rbase + j;
        float va = ((const float*)&fa)[j];
        float vb2 = ((const float*)&fb)[j];
        *(unsigned*)(Ac + row * 256 + (((slot ^ (row & 7)) << 4) | off)) = pk2bf(va, vb2);
      }
    }
  }
  __syncthreads();

  f32x4 acc[2][4];
#pragma unroll
  for (int mt = 0; mt < 2; ++mt)
#pragma unroll
    for (int nt = 0; nt < 4; ++nt) acc[mt][nt] = (f32x4){0.f, 0.f, 0.f, 0.f};

  const ushort* bp = BcT + b * 8192 + lm * 128 + lg * 8;
  auto do_k = [&](int kb) {
    short8 Bfk[4], Af[2];
#pragma unroll
    for (int nt = 0; nt < 4; ++nt)
      Bfk[nt] = *(const short8*)(bp + nt * 2048 + kb * 32);
#pragma unroll
    for (int mt = 0; mt < 2; ++mt) {
      int row = mt * 16 + lm;
      Af[mt] = *(const short8*)(Ac + row * 256 + ((((kb << 2) + lg) ^ (row & 7)) << 4));
    }
#pragma unroll
    for (int mt = 0; mt < 2; ++mt)
#pragma unroll
      for (int nt = 0; nt < 4; ++nt)
        acc[mt][nt] = __builtin_amdgcn_mfma_f32_16x16x32_bf16(Af[mt], Bfk[nt], acc[mt][nt], 0, 0, 0);
  };
  do_k(0);
  do_k(1);
#pragma unroll
  for (int mt = 0; mt < 2; ++mt) {
    float4 s4 = *(const float4*)&sinv[mt * 16 + lg * 4];
#pragma unroll
    for (int nt = 0; nt < 4; ++nt) {
      acc[mt][nt][0] *= s4.x;
      acc[mt][nt][1] *= s4.y;
      acc[mt][nt][2] *= s4.z;
      acc[mt][nt][3] *= s4.w;
    }
  }
  do_k(2);
  do_k(3);

  __syncthreads();
  float bo[4];
#pragma unroll
  for (int nt = 0; nt < 4; ++nt) bo[nt] = ob[nt * 16 + lm];
#pragma unroll
  for (int mt = 0; mt < 2; ++mt)
#pragma unroll
    for (int nt = 0; nt < 4; ++nt) {
      int o = nt * 16 + lm;
      int slot = o >> 3;
      int off = (o & 7) * 2;
#pragma unroll
      for (int r = 0; r < 4; ++r) {
        int row = mt * 16 + lg * 4 + r;
        float hv = fmaxf(acc[mt][nt][r] + bo[nt], 0.f);
        *(ushort*)(Ac + row * 128 + (((slot ^ (row & 7)) << 4) | off)) = f2bf(hv);
      }
    }
  __syncthreads();
  char* dst = (char*)hbf + ((size_t)(b * NV + v0)) * 128;
#pragma unroll
  for (int k = 0; k < 4; ++k) {
    int i = t + k * 64;
    int row = i >> 3, s = i & 7;
    *(uint4*)(dst + row * 128 + s * 16) =
        *(const uint4*)(Ac + row * 128 + ((s ^ (row & 7)) << 4));
  }
}

// ---- kernel 3: MFMA wrap-conv 32x32x16, tile (4,4,8), A depth-1 + B depth-2 -
// r14 winner + A-prefetch ping-pong (Aa/Ab): step o issues B(o+2) + A(o+1),
// MFMAs consume registers loaded one full step earlier -> the ~120cyc
// ds_read->MFMA dependency moves off the critical path. VGPR ~92 <= 170 cap.
__global__ __launch_bounds__(256, 3) void k_conv(
    const ushort* __restrict__ hbf, const ushort* __restrict__ wbf,
    const float* __restrict__ cb, const float* __restrict__ x,
    float* __restrict__ out) {
  __shared__ __align__(16) char sm[51840];
  int t = threadIdx.x;
  int lane = t & 63, wave = t >> 6;
  int lm32 = lane & 31, lh = lane >> 5;
  int kc = wave >> 1;
  int mh = wave & 1;

  int bid = blockIdx.x;                      // 3456 = 8*432, bijective swizzle
  int sw = (bid & 7) * 432 + (bid >> 3);
  int b = sw / 864, tid = sw - b * 864;
  int xt = tid / 72, rem = tid - xt * 72, yt = rem / 6, zt = rem - yt * 6;
  int x0 = xt * 4, y0 = yt * 4, z0 = zt * 8;

  const char* hbase = (const char*)hbf + (size_t)b * NV * 128;
  const ushort* wl = wbf + kc * 2048 + lane * 8;   // [off][kc][nt][kk][lane][e]

  short8 Ba[2][2], Bb[2][2], Bc[2][2];   // [nt][kk]
#pragma unroll
  for (int nt = 0; nt < 2; ++nt)
#pragma unroll
    for (int kk = 0; kk < 2; ++kk) {
      Ba[nt][kk] = *(const short8*)(wl + nt * 1024 + kk * 512);
      Bb[nt][kk] = *(const short8*)(wl + 4096 + nt * 1024 + kk * 512);
    }

  // stage halo: 360 rows (row = hx*60 + hy*10 + hz) x 8 slots, 144B-pad rows
#pragma unroll
  for (int k = 0; k < 12; ++k) {
    int c = t + k * 256;
    if (c < 2880) {
      int r = c >> 3, j = c & 7;
      int hx = r / 60, rr = r - hx * 60, hy = rr / 10, hz = rr - hy * 10;
      int gx = x0 + hx - 1; gx += (gx < 0) ? 48 : 0; gx -= (gx >= 48) ? 48 : 0;
      int gy = y0 + hy - 1; gy += (gy < 0) ? 48 : 0; gy -= (gy >= 48) ? 48 : 0;
      int gz = z0 + hz - 1; gz += (gz < 0) ? 48 : 0; gz -= (gz >= 48) ? 48 : 0;
      uint4 v = *(const uint4*)(hbase + (size_t)((gx * 2304 + gy * 48 + gz) * 128 + j * 16));
      *(uint4*)(sm + r * 144 + j * 16) = v;
    }
  }

  int yl = lm32 >> 3, zl = lm32 & 7;
  char* Abase[2];
#pragma unroll
  for (int mt = 0; mt < 2; ++mt)
    Abase[mt] = sm + (((mh * 2 + mt) * 60 + yl * 10 + zl) * 144) + (kc * 4 + lh) * 16;

  f32x16 acc[2][2];
#pragma unroll
  for (int i = 0; i < 2; ++i)
#pragma unroll
    for (int j = 0; j < 2; ++j)
#pragma unroll
      for (int q = 0; q < 16; ++q) acc[i][j][q] = 0.f;

  __syncthreads();

  // A(0) prologue (offset 0 -> aimm 0)
  short8 Aa[2][2], Ab[2][2];
#pragma unroll
  for (int mt = 0; mt < 2; ++mt)
#pragma unroll
    for (int kk = 0; kk < 2; ++kk)
      Aa[mt][kk] = *(const short8*)(Abase[mt] + kk * 32);

#define STEPC(o, Bcur, Bpre, Acur, Apre) { \
    if ((o) + 2 < 27) { \
      const ushort* p = wl + ((o) + 2) * 4096; \
      _Pragma("unroll") \
      for (int nt = 0; nt < 2; ++nt) \
        _Pragma("unroll") \
        for (int kk = 0; kk < 2; ++kk) \
          Bpre[nt][kk] = *(const short8*)(p + nt * 1024 + kk * 512); \
    } \
    if ((o) + 1 < 27) { \
      const int on = (o) + 1; \
      const int dxN = on / 9, dyzN = on - dxN * 9, dyN = dyzN / 3, dzN = dyzN - dyN * 3; \
      const int aimmN = (dxN * 60 + dyN * 10 + dzN) * 144; \
      _Pragma("unroll") \
      for (int mt = 0; mt < 2; ++mt) \
        _Pragma("unroll") \
        for (int kk = 0; kk < 2; ++kk) \
          Apre[mt][kk] = *(const short8*)(Abase[mt] + aimmN + kk * 32); \
    } \
    __builtin_amdgcn_sched_barrier(0); \
    __builtin_amdgcn_s_setprio(1); \
    _Pragma("unroll") \
    for (int kk = 0; kk < 2; ++kk) \
      _Pragma("unroll") \
      for (int mt = 0; mt < 2; ++mt) \
        _Pragma("unroll") \
        for (int nt = 0; nt < 2; ++nt) \
          acc[mt][nt] = __builtin_amdgcn_mfma_f32_32x32x16_bf16(Acur[mt][kk], Bcur[nt][kk], acc[mt][nt], 0, 0, 0); \
    __builtin_amdgcn_s_setprio(0); \
    __builtin_amdgcn_sched_barrier(0); \
  }

  STEPC(0, Ba, Bc, Aa, Ab)  STEPC(1, Bb, Ba, Ab, Aa)  STEPC(2, Bc, Bb, Aa, Ab)
  STEPC(3, Ba, Bc, Ab, Aa)  STEPC(4, Bb, Ba, Aa, Ab)  STEPC(5, Bc, Bb, Ab, Aa)
  STEPC(6, Ba, Bc, Aa, Ab)  STEPC(7, Bb, Ba, Ab, Aa)  STEPC(8, Bc, Bb, Aa, Ab)
  STEPC(9, Ba, Bc, Ab, Aa)  STEPC(10, Bb, Ba, Aa, Ab) STEPC(11, Bc, Bb, Ab, Aa)
  STEPC(12, Ba, Bc, Aa, Ab) STEPC(13, Bb, Ba, Ab, Aa) STEPC(14, Bc, Bb, Aa, Ab)
  STEPC(15, Ba, Bc, Ab, Aa) STEPC(16, Bb, Ba, Aa, Ab) STEPC(17, Bc, Bb, Ab, Aa)
  STEPC(18, Ba, Bc, Aa, Ab) STEPC(19, Bb, Ba, Ab, Aa) STEPC(20, Bc, Bb, Aa, Ab)
  STEPC(21, Ba, Bc, Ab, Aa) STEPC(22, Bb, Ba, Aa, Ab) STEPC(23, Bc, Bb, Ab, Aa)
  STEPC(24, Ba, Bc, Aa, Ab) STEPC(25, Bb, Ba, Ab, Aa) STEPC(26, Bc, Bb, Aa, Ab)
#undef STEPC

  // epilogue x-residual hoist
  const float* xb = x + (size_t)b * NC * NV;
  float* obp = out + (size_t)b * NC * NV;
  float4 xr4[8];
  size_t gaddr[8];
#pragma unroll
  for (int k = 0; k < 8; ++k) {
    int i = t + k * 256;
    int co = i >> 5, vq = i & 31;
    int v = vq * 4;
    int xl = v >> 5, rm = v & 31, yl2 = rm >> 3, zl2 = rm & 7;
    size_t g = (size_t)co * NV + (x0 + xl) * 2304 + (y0 + yl2) * 48 + (z0 + zl2);
    gaddr[k] = g;
    xr4[k] = *(const float4*)(xb + g);
  }

  __syncthreads();
  float* red = (float*)sm;
  if (kc == 1) {
#pragma unroll
    for (int mt = 0; mt < 2; ++mt)
#pragma unroll
      for (int nt = 0; nt < 2; ++nt) {
        int co = nt * 32 + lm32;
#pragma unroll
        for (int q = 0; q < 4; ++q) {
          int vox = mh * 64 + mt * 32 + q * 8 + lh * 4;
          *(float4*)&red[co * 132 + vox] = (float4){acc[mt][nt][q * 4 + 0], acc[mt][nt][q * 4 + 1],
                                                    acc[mt][nt][q * 4 + 2], acc[mt][nt][q * 4 + 3]};
        }
      }
  }
  __syncthreads();
  if (kc == 0) {
#pragma unroll
    for (int nt = 0; nt < 2; ++nt) {
      int co = nt * 32 + lm32;
      float bo = cb[co];
#pragma unroll
      for (int mt = 0; mt < 2; ++mt)
#pragma unroll
        for (int q = 0; q < 4; ++q) {
          int vox = mh * 64 + mt * 32 + q * 8 + lh * 4;
          float4 p = *(const float4*)&red[co * 132 + vox];
          float4 r;
          r.x = fmaxf(acc[mt][nt][q * 4 + 0] + p.x + bo, 0.f);
          r.y = fmaxf(acc[mt][nt][q * 4 + 1] + p.y + bo, 0.f);
          r.z = fmaxf(acc[mt][nt][q * 4 + 2] + p.z + bo, 0.f);
          r.w = fmaxf(acc[mt][nt][q * 4 + 3] + p.w + bo, 0.f);
          *(float4*)&red[co * 132 + vox] = r;
        }
    }
  }
  __syncthreads();
#pragma unroll
  for (int k = 0; k < 8; ++k) {
    int i = t + k * 256;
    int co = i >> 5, vq = i & 31;
    float4 rv = *(const float4*)&red[co * 132 + vq * 4];
    float4 o4;
    o4.x = rv.x + xr4[k].x;
    o4.y = rv.y + xr4[k].y;
    o4.z = rv.z + xr4[k].z;
    o4.w = rv.w + xr4[k].w;
    *(float4*)(obp + gaddr[k]) = o4;
  }
}

extern "C" void kernel_launch(void* const* d_in, const int* in_sizes, int n_in,
                              void* d_out, int out_size, void* d_ws, size_t ws_size,
                              hipStream_t stream) {
  const float* x = (const float*)d_in[0];
  const float* me = (const float*)d_in[1];
  const float* pos = (const float*)d_in[2];
  const float* origin = (const float*)d_in[3];
  const float* lattice = (const float*)d_in[4];
  const int* bn = (const int*)d_in[5];
  const float* vw = (const float*)d_in[6];
  const float* vb = (const float*)d_in[7];
  const float* ow = (const float*)d_in[8];
  const float* ob = (const float*)d_in[9];
  const float* cw = (const float*)d_in[10];
  const float* cbias = (const float*)d_in[11];
  float* outp = (float*)d_out;

  ushort* BcT = (ushort*)d_ws;                              // 64 KB
  ushort* wbf = (ushort*)((char*)d_ws + 65536);             // 216 KB (frag-major 32x32)
  ushort* hbf = (ushort*)((char*)d_ws + 65536 + 221184);    // 56.6 MB
  float* vmat = (float*)hbf;   // scratch inside hbf; consumed before att2 writes hbf

  k_vm<<<64, 256, 0, stream>>>(me, vw, vb, vmat);
  k_bct<<<32, 256, 0, stream>>>(ow, vmat, BcT);
  k_wt<<<(27 * 64 * 64 + 255) / 256, 256, 0, stream>>>(cw, wbf);
  k_att2<<<dim3(NV / 32, NB), 64, 0, stream>>>(x, pos, origin, lattice, bn, ob, BcT, hbf);
  k_conv<<<3456, 256, 0, stream>>>(hbf, wbf, cbias, x, outp);
}